// Round 5
// baseline (1007.372 us; speedup 1.0000x reference)
//
#include <hip/hip_runtime.h>
#include <math.h>

typedef __attribute__((ext_vector_type(8))) short short8;
typedef __attribute__((ext_vector_type(4))) float f32x4;

#define B_ 16
#define T_ 256
#define I_ 64
#define H_ 128
#define K_ 64
#define U_ 256
#define KC 16       /* rows per group */
#define NG 2        /* independent groups per block */
#define NTHR 512

#define OUT_OFF_P (B_*T_*H_)              /* 524288 */
#define OUT_OFF_LW (OUT_OFF_P + B_*K_*H_) /* 655360 */

__device__ __forceinline__ unsigned short f2bf(float x) {
    unsigned int u = __float_as_uint(x);
    u += 0x7fffu + ((u >> 16) & 1u);   // RNE for finite inputs
    return (unsigned short)(u >> 16);
}
__device__ __forceinline__ float bf2f(unsigned short u) {
    return __uint_as_float(((unsigned int)u) << 16);
}
__device__ __forceinline__ float fast_tanh(float x) {
    float e = __expf(2.0f * x);
    return 1.0f - 2.0f * __builtin_amdgcn_rcpf(e + 1.0f);
}
__device__ __forceinline__ float fast_sigmoid(float x) {
    return __builtin_amdgcn_rcpf(1.0f + __expf(-x));
}
// XOR-swizzle (r3-proven): breaks row-stride bank collisions on ds_read_b128
__device__ __forceinline__ unsigned int swz_p(unsigned int row, unsigned int col) { // [16][128] bf16
    unsigned int byte = row * 256u + col * 2u;
    byte ^= (row & 7u) << 4;
    return byte >> 1;
}
__device__ __forceinline__ unsigned int swz_b(unsigned int row, unsigned int col) { // [16][256] bf16
    unsigned int byte = row * 512u + col * 2u;
    byte ^= (row & 7u) << 4;
    return byte >> 1;
}

// raw barrier: LDS-visibility only; vmem (eps prefetch, atomics) stays in flight
#define BAR() do { asm volatile("s_waitcnt lgkmcnt(0)" ::: "memory"); \
                   __builtin_amdgcn_s_barrier(); \
                   __builtin_amdgcn_sched_barrier(0); } while (0)

#define MFMA16(a, bfrag, c) __builtin_amdgcn_mfma_f32_16x16x32_bf16((a), (bfrag), (c), 0, 0, 0)

__global__ __launch_bounds__(NTHR, 2) void pf_kernel(
    const float* __restrict__ x, const float* __restrict__ tspan,
    const float* __restrict__ eps, const float* __restrict__ Wb,
    const float* __restrict__ bb,
    const float* __restrict__ Wf1, const float* __restrict__ bf1,
    const float* __restrict__ Wf2, const float* __restrict__ bf2,
    const float* __restrict__ Wta, const float* __restrict__ bta,
    const float* __restrict__ Wtb, const float* __restrict__ btb,
    const float* __restrict__ nscale, float* __restrict__ out)
{
    const int tid  = threadIdx.x;
    const int lane = tid & 63;
    const int wv   = tid >> 6;        // wave 0..7
    const int ln15 = lane & 15;
    const int l4   = lane >> 4;
    const int bid  = blockIdx.x;      // 0..31
    const int b    = bid >> 1;
    const int k0   = (bid & 1) * (NG * KC);   // 0 or 32

    __shared__ unsigned short xw_lds[T_ * U_];        // x@Wb_x + bb, bf16 (128KB)
    __shared__ unsigned short p_bf[NG][KC * H_];      // particles (8KB)
    __shared__ unsigned short bbk_bf[NG][KC * U_];    // backbone acts (16KB)
    __shared__ float ts_lds[T_];                      // (1KB)

    for (int i = tid; i < NG * KC * H_; i += NTHR) ((unsigned short*)p_bf)[i] = 0;
    for (int i = tid; i < T_; i += NTHR) ts_lds[i] = tspan[b * T_ + i];

    // ---- GEMM1 particle-part weights (Wb rows 64..191), wave owns cols [wv*32,+32) ----
    short8 B1p[4][2];
    #pragma unroll
    for (int kt = 0; kt < 4; ++kt) {
        #pragma unroll
        for (int ct = 0; ct < 2; ++ct) {
            short8 f;
            const int col = wv * 32 + ct * 16 + ln15;
            #pragma unroll
            for (int j = 0; j < 8; ++j)
                f[j] = (short)f2bf(Wb[(I_ + kt * 32 + l4 * 8 + j) * U_ + col]);
            B1p[kt][ct] = f;
        }
    }
    // ---- GEMM2 weights: wave owns h cols [wv*16,+16) for ALL 4 heads ----
    const float* Whp[4] = {Wf1, Wf2, Wta, Wtb};
    const int hc = wv * 16 + ln15;
    short8 B2[4][8];
    #pragma unroll
    for (int hd = 0; hd < 4; ++hd) {
        #pragma unroll
        for (int kt = 0; kt < 8; ++kt) {
            short8 f;
            #pragma unroll
            for (int j = 0; j < 8; ++j)
                f[j] = (short)f2bf(Whp[hd][(kt * 32 + l4 * 8 + j) * H_ + hc]);
            B2[hd][kt] = f;
        }
    }
    const float bf1c = bf1[hc], bf2c = bf2[hc];
    const float btac = bta[hc], btbc = btb[hc];
    const float nscc = nscale[hc];

    // ---- prologue: xw[t][v] = x[b,t,:] @ Wb_x + bb  (bf16 into LDS) ----
    {
        short8 Bx[2][2];
        #pragma unroll
        for (int kt = 0; kt < 2; ++kt) {
            #pragma unroll
            for (int ct = 0; ct < 2; ++ct) {
                short8 f;
                const int col = wv * 32 + ct * 16 + ln15;
                #pragma unroll
                for (int j = 0; j < 8; ++j)
                    f[j] = (short)f2bf(Wb[(kt * 32 + l4 * 8 + j) * U_ + col]);
                Bx[kt][ct] = f;
            }
        }
        const float bbc0 = bb[wv * 32 + ln15];
        const float bbc1 = bb[wv * 32 + 16 + ln15];
        const f32x4 z4 = {0.f, 0.f, 0.f, 0.f};
        for (int tt = 0; tt < 16; ++tt) {
            const int t0 = tt * 16;
            short8 axf[2];
            #pragma unroll
            for (int kt = 0; kt < 2; ++kt) {
                const float* xp = &x[(size_t)(b * T_ + t0 + ln15) * I_ + kt * 32 + l4 * 8];
                short8 f;
                #pragma unroll
                for (int j = 0; j < 8; ++j) f[j] = (short)f2bf(xp[j]);
                axf[kt] = f;
            }
            f32x4 xa0 = z4, xa1 = z4;
            xa0 = MFMA16(axf[0], Bx[0][0], xa0); xa1 = MFMA16(axf[0], Bx[0][1], xa1);
            xa0 = MFMA16(axf[1], Bx[1][0], xa0); xa1 = MFMA16(axf[1], Bx[1][1], xa1);
            #pragma unroll
            for (int r = 0; r < 4; ++r) {
                const int trow = t0 + l4 * 4 + r;
                xw_lds[trow * U_ + wv * 32 + ln15]      = f2bf(xa0[r] + bbc0);
                xw_lds[trow * U_ + wv * 32 + 16 + ln15] = f2bf(xa1[r] + bbc1);
            }
        }
    }

    // pin persistent fragments
    #pragma unroll
    for (int kt = 0; kt < 4; ++kt) asm volatile("" : "+v"(B1p[kt][0]), "+v"(B1p[kt][1]));
    #pragma unroll
    for (int hd = 0; hd < 4; ++hd) {
        #pragma unroll
        for (int kt = 0; kt < 8; ++kt) asm volatile("" : "+v"(B2[hd][kt]));
    }

    if ((bid & 1) == 0 && tid < K_)
        out[OUT_OFF_LW + b * K_ + tid] = -4.1588830833596715f; // -log(64)

    __syncthreads();   // full drain once after prologue

    // eps lane base per group: ((t*B + b)*K + k0 + g*16 + l4*4 + r)*H + hc
    const float* epg0 = eps + ((size_t)(b * K_ + k0 + 0 * KC + l4 * 4)) * H_ + hc;
    const float* epg1 = eps + ((size_t)(b * K_ + k0 + 1 * KC + l4 * 4)) * H_ + hc;
    float ec0[4], ec1[4];
    #pragma unroll
    for (int r = 0; r < 4; ++r) { ec0[r] = epg0[r * H_]; ec1[r] = epg1[r * H_]; }
    float tscur = ts_lds[0];

    const f32x4 zero4 = {0.f, 0.f, 0.f, 0.f};

    for (int t = 0; t < T_; ++t) {
        // ---- prefetch next-step inputs (1 step ahead; never drained at BAR) ----
        const int tn = (t + 1 < T_) ? t + 1 : t;
        const size_t soff = (size_t)tn * (B_ * K_ * H_);
        float en0[4], en1[4];
        #pragma unroll
        for (int r = 0; r < 4; ++r) { en0[r] = epg0[soff + r * H_]; en1[r] = epg1[soff + r * H_]; }
        const float tsn = ts_lds[tn];

        // ---- phase 1: GEMM1 particle part for BOTH groups (x-part = xw from LDS) ----
        const float xw0 = bf2f(xw_lds[t * U_ + wv * 32 + ln15]);
        const float xw1 = bf2f(xw_lds[t * U_ + wv * 32 + 16 + ln15]);
        f32x4 a00 = {xw0, xw0, xw0, xw0}, a01 = {xw1, xw1, xw1, xw1};
        f32x4 a10 = a00, a11 = a01;
        #pragma unroll
        for (int kt = 0; kt < 4; ++kt) {
            const short8 ap0 = *(const short8*)&p_bf[0][swz_p(ln15, kt * 32 + l4 * 8)];
            const short8 ap1 = *(const short8*)&p_bf[1][swz_p(ln15, kt * 32 + l4 * 8)];
            a00 = MFMA16(ap0, B1p[kt][0], a00);
            a01 = MFMA16(ap0, B1p[kt][1], a01);
            a10 = MFMA16(ap1, B1p[kt][0], a10);
            a11 = MFMA16(ap1, B1p[kt][1], a11);
        }
        #pragma unroll
        for (int r = 0; r < 4; ++r) {
            const int row = l4 * 4 + r;
            bbk_bf[0][swz_b(row, wv * 32 + ln15)]      = f2bf(1.7159f * fast_tanh(0.666f * a00[r]));
            bbk_bf[0][swz_b(row, wv * 32 + 16 + ln15)] = f2bf(1.7159f * fast_tanh(0.666f * a01[r]));
            bbk_bf[1][swz_b(row, wv * 32 + ln15)]      = f2bf(1.7159f * fast_tanh(0.666f * a10[r]));
            bbk_bf[1][swz_b(row, wv * 32 + 16 + ln15)] = f2bf(1.7159f * fast_tanh(0.666f * a11[r]));
        }
        BAR();

        // ---- phase 2: GEMM2 for both groups (4 heads each) + in-register combine ----
        f32x4 f1a = zero4, f2a = zero4, taa = zero4, tba = zero4;
        f32x4 f1b = zero4, f2b = zero4, tab = zero4, tbb = zero4;
        #pragma unroll
        for (int kt = 0; kt < 8; ++kt) {
            const short8 qa = *(const short8*)&bbk_bf[0][swz_b(ln15, kt * 32 + l4 * 8)];
            const short8 qb = *(const short8*)&bbk_bf[1][swz_b(ln15, kt * 32 + l4 * 8)];
            f1a = MFMA16(qa, B2[0][kt], f1a);
            f2a = MFMA16(qa, B2[1][kt], f2a);
            taa = MFMA16(qa, B2[2][kt], taa);
            tba = MFMA16(qa, B2[3][kt], tba);
            f1b = MFMA16(qb, B2[0][kt], f1b);
            f2b = MFMA16(qb, B2[1][kt], f2b);
            tab = MFMA16(qb, B2[2][kt], tab);
            tbb = MFMA16(qb, B2[3][kt], tbb);
        }
        const float sq = sqrtf(tscur);
        float psum = 0.f;
        const bool last = (t == T_ - 1);
        #pragma unroll
        for (int r = 0; r < 4; ++r) {
            const int row = l4 * 4 + r;
            {   // group 0
                const float f1v = fast_tanh(f1a[r] + bf1c);
                const float f2v = fast_tanh(f2a[r] + bf2c);
                const float tiv = fast_sigmoid((taa[r] + btac) * tscur + (tba[r] + btbc));
                const float np  = f1v + tiv * (f2v - f1v) + nscc * sq * ec0[r];
                p_bf[0][swz_p(row, hc)] = f2bf(np);
                psum += np;
                if (last) out[OUT_OFF_P + (size_t)(b * K_ + k0 + row) * H_ + hc] = np;
            }
            {   // group 1
                const float f1v = fast_tanh(f1b[r] + bf1c);
                const float f2v = fast_tanh(f2b[r] + bf2c);
                const float tiv = fast_sigmoid((tab[r] + btac) * tscur + (tbb[r] + btbc));
                const float np  = f1v + tiv * (f2v - f1v) + nscc * sq * ec1[r];
                p_bf[1][swz_p(row, hc)] = f2bf(np);
                psum += np;
                if (last) out[OUT_OFF_P + (size_t)(b * K_ + k0 + KC + row) * H_ + hc] = np;
            }
        }
        // block partial mean (32 of 64 rows): reduce over l4 groups, 1 atomic/16 lanes
        psum += __shfl_xor(psum, 16);
        psum += __shfl_xor(psum, 32);
        if (lane < 16)
            atomicAdd(&out[(size_t)(b * T_ + t) * H_ + wv * 16 + lane], psum * (1.0f / 64.0f));

        #pragma unroll
        for (int r = 0; r < 4; ++r) { ec0[r] = en0[r]; ec1[r] = en1[r]; }
        tscur = tsn;
        BAR();
    }
}

extern "C" void kernel_launch(void* const* d_in, const int* in_sizes, int n_in,
                              void* d_out, int out_size, void* d_ws, size_t ws_size,
                              hipStream_t stream) {
    const float* x    = (const float*)d_in[0];
    const float* tsp  = (const float*)d_in[1];
    const float* eps  = (const float*)d_in[2];
    const float* Wb   = (const float*)d_in[3];
    const float* bb   = (const float*)d_in[4];
    const float* Wf1  = (const float*)d_in[5];
    const float* bf1  = (const float*)d_in[6];
    const float* Wf2  = (const float*)d_in[7];
    const float* bf2  = (const float*)d_in[8];
    const float* Wta  = (const float*)d_in[9];
    const float* bta  = (const float*)d_in[10];
    const float* Wtb  = (const float*)d_in[11];
    const float* btb  = (const float*)d_in[12];
    const float* nsc  = (const float*)d_in[13];
    float* out = (float*)d_out;

    // outputs region is accumulated with atomics -> zero every launch
    (void)hipMemsetAsync(d_out, 0, (size_t)OUT_OFF_P * sizeof(float), stream);
    pf_kernel<<<dim3(32), dim3(NTHR), 0, stream>>>(
        x, tsp, eps, Wb, bb, Wf1, bf1, Wf2, bf2, Wta, bta, Wtb, btb, nsc, out);
}

// Round 6
// 493.938 us; speedup vs baseline: 2.0395x; 2.0395x over previous
//
#include <hip/hip_runtime.h>
#include <math.h>

typedef __attribute__((ext_vector_type(8))) short short8;
typedef __attribute__((ext_vector_type(4))) float f32x4;

#define B_ 16
#define T_ 256
#define I_ 64
#define H_ 128
#define K_ 64
#define U_ 256
#define KC 16
#define NTHR 512

#define OUT_OFF_P (B_*T_*H_)              /* 524288 */
#define OUT_OFF_LW (OUT_OFF_P + B_*K_*H_) /* 655360 */

__device__ __forceinline__ unsigned short f2bf(float x) {
    unsigned int u = __float_as_uint(x);
    u += 0x7fffu + ((u >> 16) & 1u);   // RNE for finite inputs
    return (unsigned short)(u >> 16);
}
__device__ __forceinline__ float bf2f(unsigned short u) {
    return __uint_as_float(((unsigned int)u) << 16);
}
__device__ __forceinline__ float fast_tanh(float x) {
    float e = __expf(2.0f * x);
    return 1.0f - 2.0f * __builtin_amdgcn_rcpf(e + 1.0f);
}
__device__ __forceinline__ float fast_sigmoid(float x) {
    return __builtin_amdgcn_rcpf(1.0f + __expf(-x));
}
// XOR-swizzle (R3-proven): breaks row-stride bank collisions on ds_read_b128
__device__ __forceinline__ unsigned int swzbyte_p(unsigned int row, unsigned int col) { // [16][128] bf16
    return (row * 256u + col * 2u) ^ ((row & 7u) << 4);
}
__device__ __forceinline__ unsigned int swzbyte_b(unsigned int row, unsigned int pos) { // [16][256] bf16 (pos space)
    return (row * 512u + pos * 2u) ^ ((row & 7u) << 4);
}

// raw barrier: LDS-visibility only; vmem (eps/xw prefetch, atomics) stays in flight.
// trailing empty asm = compile-time fence so post-barrier LDS reads can't hoist.
#define BAR() do { asm volatile("s_waitcnt lgkmcnt(0)" ::: "memory"); \
                   __builtin_amdgcn_s_barrier(); \
                   asm volatile("" ::: "memory"); } while (0)

#define MFMA16(a, bfrag, c) __builtin_amdgcn_mfma_f32_16x16x32_bf16((a), (bfrag), (c), 0, 0, 0)

// ---------------- kernel 1: xw[b,t,u] = x[b,t,:] @ Wb[0:64,:] + bb  (bf16) ----------------
__global__ __launch_bounds__(256) void xw_kernel(
    const float* __restrict__ x, const float* __restrict__ Wb,
    const float* __restrict__ bb, unsigned short* __restrict__ xw)
{
    const int tid  = threadIdx.x;
    const int lane = tid & 63;
    const int wv   = tid >> 6;       // 0..3, owns cols [wv*64, +64)
    const int ln15 = lane & 15;
    const int l4   = lane >> 4;
    const int bid  = blockIdx.x;     // 256 blocks = b(16) x ttile(16)
    const int b    = bid >> 4;
    const int t0   = (bid & 15) * 16;

    short8 Bx[2][4];
    float bbc[4];
    #pragma unroll
    for (int kt = 0; kt < 2; ++kt) {
        #pragma unroll
        for (int ct = 0; ct < 4; ++ct) {
            short8 f;
            const int col = wv * 64 + ct * 16 + ln15;
            #pragma unroll
            for (int j = 0; j < 8; ++j)
                f[j] = (short)f2bf(Wb[(kt * 32 + l4 * 8 + j) * U_ + col]);
            Bx[kt][ct] = f;
        }
    }
    #pragma unroll
    for (int ct = 0; ct < 4; ++ct) bbc[ct] = bb[wv * 64 + ct * 16 + ln15];

    short8 ax[2];
    #pragma unroll
    for (int kt = 0; kt < 2; ++kt) {
        const float* xp = &x[(size_t)(b * T_ + t0 + ln15) * I_ + kt * 32 + l4 * 8];
        short8 f;
        #pragma unroll
        for (int j = 0; j < 8; ++j) f[j] = (short)f2bf(xp[j]);
        ax[kt] = f;
    }
    const f32x4 z4 = {0.f, 0.f, 0.f, 0.f};
    f32x4 acc[4] = {z4, z4, z4, z4};
    #pragma unroll
    for (int kt = 0; kt < 2; ++kt) {
        #pragma unroll
        for (int ct = 0; ct < 4; ++ct) acc[ct] = MFMA16(ax[kt], Bx[kt][ct], acc[ct]);
    }
    #pragma unroll
    for (int ct = 0; ct < 4; ++ct) {
        #pragma unroll
        for (int r = 0; r < 4; ++r) {
            const int trow = t0 + l4 * 4 + r;
            xw[(size_t)(b * T_ + trow) * U_ + wv * 64 + ct * 16 + ln15] = f2bf(acc[ct][r] + bbc[ct]);
        }
    }
}

// ---------------- kernel 2: the recurrence ----------------
__global__ __launch_bounds__(NTHR, 2) void pf_kernel(
    const unsigned short* __restrict__ xw, const float* __restrict__ tspan,
    const float* __restrict__ eps, const float* __restrict__ Wb,
    const float* __restrict__ Wf1, const float* __restrict__ bf1,
    const float* __restrict__ Wf2, const float* __restrict__ bf2,
    const float* __restrict__ Wta, const float* __restrict__ bta,
    const float* __restrict__ Wtb, const float* __restrict__ btb,
    const float* __restrict__ nscale, float* __restrict__ out)
{
    const int tid  = threadIdx.x;
    const int lane = tid & 63;
    const int wv   = tid >> 6;        // wave 0..7
    const int ln15 = lane & 15;
    const int l4   = lane >> 4;
    const int bid  = blockIdx.x;      // 0..63
    const int b    = bid >> 2;
    const int k0   = (bid & 3) * KC;

    __shared__ unsigned short p_bf[KC * H_];     // particles bf16, swizzled (4KB)
    __shared__ unsigned short bbk_bf[KC * U_];   // backbone acts bf16, swizzled+col-permuted (8KB)
    __shared__ float ts_lds[T_];                 // (1KB)

    for (int i = tid; i < KC * H_; i += NTHR) p_bf[i] = 0;
    for (int i = tid; i < T_; i += NTHR) ts_lds[i] = tspan[b * T_ + i];

    // ---- GEMM1 particle-part weights (Wb rows 64..191), wave owns cols [wv*32,+32) ----
    short8 B1p[4][2];
    #pragma unroll
    for (int kt = 0; kt < 4; ++kt) {
        #pragma unroll
        for (int ct = 0; ct < 2; ++ct) {
            short8 f;
            const int col = wv * 32 + ct * 16 + ln15;
            #pragma unroll
            for (int j = 0; j < 8; ++j)
                f[j] = (short)f2bf(Wb[(I_ + kt * 32 + l4 * 8 + j) * U_ + col]);
            B1p[kt][ct] = f;
        }
    }
    // ---- GEMM2 weights: wave owns h cols [wv*16,+16) for ALL 4 heads ----
    // bbk LDS is column-PERMUTED within each 32-block: col c -> pos 2*(c&15)+(c>>4),
    // so B-fragment element j (pos = l4*8+j) maps to k = kt*32 + (pos>>1) + ((pos&1)<<4).
    const float* Whp[4] = {Wf1, Wf2, Wta, Wtb};
    const int hc = wv * 16 + ln15;
    short8 B2[4][8];
    #pragma unroll
    for (int hd = 0; hd < 4; ++hd) {
        #pragma unroll
        for (int kt = 0; kt < 8; ++kt) {
            short8 f;
            #pragma unroll
            for (int j = 0; j < 8; ++j) {
                const int pos = l4 * 8 + j;
                const int kg  = kt * 32 + (pos >> 1) + ((pos & 1) << 4);
                f[j] = (short)f2bf(Whp[hd][kg * H_ + hc]);
            }
            B2[hd][kt] = f;
        }
    }
    const float bf1c = bf1[hc], bf2c = bf2[hc];
    const float btac = bta[hc], btbc = btb[hc];
    const float nscc = nscale[hc];

    if ((bid & 3) == 0 && tid < K_)
        out[OUT_OFF_LW + b * K_ + tid] = -4.1588830833596715f; // -log(64)

    __syncthreads();   // full drain once after prologue

    // per-step scalar operands, prefetched one step ahead into registers
    const float* ep0 = eps + ((size_t)(b * K_ + k0 + l4 * 4)) * H_ + hc;       // + t*B*K*H
    const unsigned short* xwp = xw + (size_t)b * T_ * U_ + wv * 32 + ln15;     // + t*U
    float ecur[4];
    #pragma unroll
    for (int r = 0; r < 4; ++r) ecur[r] = ep0[r * H_];
    float xw0c = bf2f(xwp[0]), xw1c = bf2f(xwp[16]);
    float tscur = ts_lds[0];

    const f32x4 zero4 = {0.f, 0.f, 0.f, 0.f};

    for (int t = 0; t < T_; ++t) {
        // ---- prefetch step t+1 inputs (never drained at BAR; consumed next iter) ----
        const int tn = (t + 1 < T_) ? t + 1 : t;
        const float* epn = ep0 + (size_t)tn * (B_ * K_ * H_);
        float enext[4];
        #pragma unroll
        for (int r = 0; r < 4; ++r) enext[r] = epn[r * H_];
        const float xw0n = bf2f(xwp[tn * U_]), xw1n = bf2f(xwp[tn * U_ + 16]);
        const float tsn = ts_lds[tn];

        // ---- phase 1: GEMM1 particle part; acc init = xw (x-part + bias, precomputed) ----
        f32x4 acc0 = {xw0c, xw0c, xw0c, xw0c};
        f32x4 acc1 = {xw1c, xw1c, xw1c, xw1c};
        #pragma unroll
        for (int kt = 0; kt < 4; ++kt) {
            const short8 ap = *(const short8*)((const char*)p_bf + swzbyte_p(ln15, kt * 32 + l4 * 8));
            acc0 = MFMA16(ap, B1p[kt][0], acc0);
            acc1 = MFMA16(ap, B1p[kt][1], acc1);
        }
        #pragma unroll
        for (int r = 0; r < 4; ++r) {                 // C: row=(l>>4)*4+r, col=l&15
            const int row = l4 * 4 + r;
            const unsigned int q0 = f2bf(1.7159f * fast_tanh(0.666f * acc0[r]));
            const unsigned int q1 = f2bf(1.7159f * fast_tanh(0.666f * acc1[r]));
            // packed write: cols (wv*32+ln15, wv*32+16+ln15) -> pos (2*ln15, 2*ln15+1)
            *(unsigned int*)((char*)bbk_bf + swzbyte_b(row, wv * 32 + 2 * ln15)) = q0 | (q1 << 16);
        }
        BAR();

        // ---- phase 2: GEMM2 (4 heads, own 16 h-cols) + in-register combine ----
        f32x4 a_f1 = zero4, a_f2 = zero4, a_ta = zero4, a_tb = zero4;
        #pragma unroll
        for (int kt = 0; kt < 8; ++kt) {
            const short8 a = *(const short8*)((const char*)bbk_bf + swzbyte_b(ln15, kt * 32 + l4 * 8));
            a_f1 = MFMA16(a, B2[0][kt], a_f1);
            a_f2 = MFMA16(a, B2[1][kt], a_f2);
            a_ta = MFMA16(a, B2[2][kt], a_ta);
            a_tb = MFMA16(a, B2[3][kt], a_tb);
        }
        const float sq = sqrtf(tscur);
        float psum = 0.f;
        const bool last = (t == T_ - 1);
        #pragma unroll
        for (int r = 0; r < 4; ++r) {
            const int row = l4 * 4 + r;
            const float f1v = fast_tanh(a_f1[r] + bf1c);
            const float f2v = fast_tanh(a_f2[r] + bf2c);
            const float tiv = fast_sigmoid((a_ta[r] + btac) * tscur + (a_tb[r] + btbc));
            const float np  = f1v + tiv * (f2v - f1v) + nscc * sq * ecur[r];
            *(unsigned short*)((char*)p_bf + swzbyte_p(row, hc)) = f2bf(np);
            psum += np;
            if (last)
                out[OUT_OFF_P + (size_t)(b * K_ + k0 + row) * H_ + hc] = np;
        }
        // block partial mean (16 rows): sum over l4 groups, 1 atomic per 16 lanes
        psum += __shfl_xor(psum, 16);
        psum += __shfl_xor(psum, 32);
        if (lane < 16)
            atomicAdd(&out[(size_t)(b * T_ + t) * H_ + wv * 16 + lane], psum * (1.0f / 64.0f));

        #pragma unroll
        for (int r = 0; r < 4; ++r) ecur[r] = enext[r];
        xw0c = xw0n; xw1c = xw1n;
        tscur = tsn;
        BAR();
    }
}

extern "C" void kernel_launch(void* const* d_in, const int* in_sizes, int n_in,
                              void* d_out, int out_size, void* d_ws, size_t ws_size,
                              hipStream_t stream) {
    const float* x    = (const float*)d_in[0];
    const float* tsp  = (const float*)d_in[1];
    const float* eps  = (const float*)d_in[2];
    const float* Wb   = (const float*)d_in[3];
    const float* bb   = (const float*)d_in[4];
    const float* Wf1  = (const float*)d_in[5];
    const float* bf1  = (const float*)d_in[6];
    const float* Wf2  = (const float*)d_in[7];
    const float* bf2  = (const float*)d_in[8];
    const float* Wta  = (const float*)d_in[9];
    const float* bta  = (const float*)d_in[10];
    const float* Wtb  = (const float*)d_in[11];
    const float* btb  = (const float*)d_in[12];
    const float* nsc  = (const float*)d_in[13];
    float* out = (float*)d_out;
    unsigned short* xw = (unsigned short*)d_ws;   // B*T*U bf16 = 2MB scratch

    // outputs region is accumulated with atomics -> zero every launch
    (void)hipMemsetAsync(d_out, 0, (size_t)OUT_OFF_P * sizeof(float), stream);
    xw_kernel<<<dim3(256), dim3(256), 0, stream>>>(x, Wb, bb, xw);
    pf_kernel<<<dim3(64), dim3(NTHR), 0, stream>>>(
        xw, tsp, eps, Wb, Wf1, bf1, Wf2, bf2, Wta, bta, Wtb, btb, nsc, out);
}